// Round 1
// baseline (193.063 us; speedup 1.0000x reference)
//
#include <hip/hip_runtime.h>
#include <hip/hip_bf16.h>

#define S_LEN   2048
#define D_DIM   64
#define BLOCK_Q 128
#define BLOCK_K 32

typedef __attribute__((ext_vector_type(8))) short  short8;
typedef __attribute__((ext_vector_type(4))) float  floatx4;

#define KLD   72   // K tile leading dim (bf16 elems), rows = 32 keys       -> 144B rows (16B aligned)
#define VTLD  40   // V^T tile leading dim (bf16 elems), rows = 64 d        -> 80B rows (16B aligned)
#define PLD   40   // P tile leading dim (bf16 elems), rows = 32 q per wave -> 80B rows (16B aligned)
#define OLD   65   // epilogue fp32 leading dim (odd to spread banks)

#define KOFF   0
#define VTOFF  4608            // 32*72*2
#define POFF   9728            // 4608 + 64*40*2
#define SMEM_BYTES 19968       // 9728 + 4*32*40*2

__device__ __forceinline__ short f2bf(float x) {
  union { __hip_bfloat16 h; short s; } u;
  u.h = __float2bfloat16(x);
  return u.s;
}

__global__ __launch_bounds__(256, 2)
void fa_fwd(const float* __restrict__ Qg, const float* __restrict__ Kg,
            const float* __restrict__ Vg, float* __restrict__ Og)
{
  __shared__ char smem[SMEM_BYTES];
  short* Klds  = (short*)(smem + KOFF);
  short* Vtlds = (short*)(smem + VTOFF);

  const int tid  = threadIdx.x;
  const int wv   = tid >> 6;
  const int lane = tid & 63;
  const int col  = lane & 15;
  const int quad = lane >> 4;
  short* Plds = (short*)(smem + POFF) + wv * (32 * PLD);

  const int bh   = blockIdx.x >> 4;            // (b*H + h)
  const int qblk = 15 - (blockIdx.x & 15);     // big blocks first (causal tail)
  const int q0   = qblk * BLOCK_Q;
  const int qw0  = q0 + wv * 32;

  const float qscale = 0.18033688011112042f;   // log2(e) / sqrt(64): exp2-domain softmax

  // ---- Q preload into B-operand fragments (b_frag[j] = Q[q=lane&15][d0+quad*8+j]) ----
  short8 qfrag[2][2];
#pragma unroll
  for (int qt = 0; qt < 2; ++qt) {
#pragma unroll
    for (int h = 0; h < 2; ++h) {
      const float* qp = Qg + (size_t)(bh * S_LEN + qw0 + qt * 16 + col) * D_DIM + h * 32 + quad * 8;
      float4 a = *(const float4*)qp;
      float4 b = *(const float4*)(qp + 4);
      short8 f;
      f[0]=f2bf(a.x*qscale); f[1]=f2bf(a.y*qscale); f[2]=f2bf(a.z*qscale); f[3]=f2bf(a.w*qscale);
      f[4]=f2bf(b.x*qscale); f[5]=f2bf(b.y*qscale); f[6]=f2bf(b.z*qscale); f[7]=f2bf(b.w*qscale);
      qfrag[qt][h] = f;
    }
  }

  floatx4 o[2][4];          // O^T accumulators: o[qt][dt], row=d_local (quad*4+r), col=q_local
#pragma unroll
  for (int qt = 0; qt < 2; ++qt)
#pragma unroll
    for (int dt = 0; dt < 4; ++dt)
      o[qt][dt] = (floatx4){0.f, 0.f, 0.f, 0.f};
  float m_st[2] = {-1e30f, -1e30f};
  float l_st[2] = {0.f, 0.f};

  const int k_end = q0 + BLOCK_Q;              // causal: keys beyond the q-block never needed

  for (int kb = 0; kb < k_end; kb += BLOCK_K) {
    __syncthreads();
    // ---- stage K tile as bf16 [32][KLD] ----
    {
      const int kr = tid >> 3;
      const int dc = (tid & 7) * 8;
      const float* kp = Kg + (size_t)(bh * S_LEN + kb + kr) * D_DIM + dc;
      float4 a = *(const float4*)kp;
      float4 b = *(const float4*)(kp + 4);
      short8 f;
      f[0]=f2bf(a.x); f[1]=f2bf(a.y); f[2]=f2bf(a.z); f[3]=f2bf(a.w);
      f[4]=f2bf(b.x); f[5]=f2bf(b.y); f[6]=f2bf(b.z); f[7]=f2bf(b.w);
      *(short8*)&Klds[kr * KLD + dc] = f;
    }
    // ---- stage V^T tile as bf16 [64][VTLD]: pair-packed b32 writes ----
    {
      const int k0 = (tid >> 4) * 2;
      const int d  = (tid & 15) * 4;
      const float* vp = Vg + (size_t)(bh * S_LEN + kb + k0) * D_DIM + d;
      float4 a = *(const float4*)vp;
      float4 b = *(const float4*)(vp + D_DIM);
      float av[4] = {a.x, a.y, a.z, a.w};
      float bv[4] = {b.x, b.y, b.z, b.w};
#pragma unroll
      for (int i = 0; i < 4; ++i) {
        unsigned int lo = (unsigned short)f2bf(av[i]);
        unsigned int hi = (unsigned short)f2bf(bv[i]);
        *(unsigned int*)&Vtlds[(d + i) * VTLD + k0] = lo | (hi << 16);
      }
    }
    __syncthreads();

    // ---- S^T = K · Q^T  (A = K rows, B = Q rows; C: row=key_local, col=q_local) ----
    short8 kfrag[2][2];
#pragma unroll
    for (int kt = 0; kt < 2; ++kt)
#pragma unroll
      for (int h = 0; h < 2; ++h)
        kfrag[kt][h] = *(short8*)&Klds[(kt * 16 + col) * KLD + h * 32 + quad * 8];

    floatx4 st[2][2];
#pragma unroll
    for (int qt = 0; qt < 2; ++qt)
#pragma unroll
      for (int kt = 0; kt < 2; ++kt) {
        floatx4 c = {0.f, 0.f, 0.f, 0.f};
        c = __builtin_amdgcn_mfma_f32_16x16x32_bf16(kfrag[kt][0], qfrag[qt][0], c, 0, 0, 0);
        c = __builtin_amdgcn_mfma_f32_16x16x32_bf16(kfrag[kt][1], qfrag[qt][1], c, 0, 0, 0);
        st[qt][kt] = c;
      }

    // ---- online softmax (exp2 domain), per q-tile; reduction is per-column ----
#pragma unroll
    for (int qt = 0; qt < 2; ++qt) {
      const int qg = qw0 + qt * 16 + col;
#pragma unroll
      for (int kt = 0; kt < 2; ++kt) {
        const int kbase = kb + kt * 16 + quad * 4;
#pragma unroll
        for (int r = 0; r < 4; ++r)
          if (kbase + r > qg) st[qt][kt][r] = -1e30f;
      }
      float mx = st[qt][0][0];
#pragma unroll
      for (int kt = 0; kt < 2; ++kt)
#pragma unroll
        for (int r = 0; r < 4; ++r) mx = fmaxf(mx, st[qt][kt][r]);
      mx = fmaxf(mx, __shfl_xor(mx, 16));
      mx = fmaxf(mx, __shfl_xor(mx, 32));
      const float mnew  = fmaxf(m_st[qt], mx);
      const float alpha = __builtin_amdgcn_exp2f(m_st[qt] - mnew);
      m_st[qt] = mnew;
      float sum = 0.f;
#pragma unroll
      for (int kt = 0; kt < 2; ++kt)
#pragma unroll
        for (int r = 0; r < 4; ++r) {
          const float p = __builtin_amdgcn_exp2f(st[qt][kt][r] - mnew);
          st[qt][kt][r] = p;
          sum += p;
        }
      sum += __shfl_xor(sum, 16);
      sum += __shfl_xor(sum, 32);
      l_st[qt] = l_st[qt] * alpha + sum;
#pragma unroll
      for (int dt = 0; dt < 4; ++dt)
#pragma unroll
        for (int r = 0; r < 4; ++r) o[qt][dt][r] *= alpha;
      // P^T (C-layout) -> LDS as P[q][k] bf16, pair-packed b32 writes (adjacent r = adjacent k)
#pragma unroll
      for (int kt = 0; kt < 2; ++kt)
#pragma unroll
        for (int pr = 0; pr < 2; ++pr) {
          unsigned int lo = (unsigned short)f2bf(st[qt][kt][2 * pr]);
          unsigned int hi = (unsigned short)f2bf(st[qt][kt][2 * pr + 1]);
          *(unsigned int*)&Plds[(qt * 16 + col) * PLD + kt * 16 + quad * 4 + 2 * pr] = lo | (hi << 16);
        }
    }

    // ---- O^T += V^T · P^T  (A = V^T rows from Vtlds, B = P rows from Plds) ----
    short8 vfrag[4];
#pragma unroll
    for (int dt = 0; dt < 4; ++dt)
      vfrag[dt] = *(short8*)&Vtlds[(dt * 16 + col) * VTLD + quad * 8];
#pragma unroll
    for (int qt = 0; qt < 2; ++qt) {
      short8 pfrag = *(short8*)&Plds[(qt * 16 + col) * PLD + quad * 8];
#pragma unroll
      for (int dt = 0; dt < 4; ++dt)
        o[qt][dt] = __builtin_amdgcn_mfma_f32_16x16x32_bf16(vfrag[dt], pfrag, o[qt][dt], 0, 0, 0);
    }
  }

  // ---- epilogue: normalize, transpose through LDS, coalesced float4 stores ----
  __syncthreads();                      // staging LDS reusable now
  float* Olds = (float*)smem + wv * (16 * OLD);
#pragma unroll
  for (int qt = 0; qt < 2; ++qt) {
    const float inv = 1.0f / l_st[qt];  // per-column (per-query), lane-local
#pragma unroll
    for (int dt = 0; dt < 4; ++dt)
#pragma unroll
      for (int r = 0; r < 4; ++r)
        Olds[col * OLD + dt * 16 + quad * 4 + r] = o[qt][dt][r] * inv;
#pragma unroll
    for (int it = 0; it < 4; ++it) {
      const int ql = quad + it * 4;
      float4 w;
      w.x = Olds[ql * OLD + col * 4 + 0];
      w.y = Olds[ql * OLD + col * 4 + 1];
      w.z = Olds[ql * OLD + col * 4 + 2];
      w.w = Olds[ql * OLD + col * 4 + 3];
      *(float4*)(Og + (size_t)(bh * S_LEN + qw0 + qt * 16 + ql) * D_DIM + col * 4) = w;
    }
  }
}

extern "C" void kernel_launch(void* const* d_in, const int* in_sizes, int n_in,
                              void* d_out, int out_size, void* d_ws, size_t ws_size,
                              hipStream_t stream) {
  const float* Q = (const float*)d_in[0];
  const float* K = (const float*)d_in[1];
  const float* V = (const float*)d_in[2];
  float* O = (float*)d_out;
  dim3 grid(32 * (S_LEN / BLOCK_Q));   // 512 blocks: (b*H+h) * 16 q-blocks
  dim3 block(256);
  hipLaunchKernelGGL(fa_fwd, grid, block, 0, stream, Q, K, V, O);
}

// Round 2
// 152.735 us; speedup vs baseline: 1.2640x; 1.2640x over previous
//
#include <hip/hip_runtime.h>
#include <hip/hip_bf16.h>

#define S_LEN   2048
#define D_DIM   64
#define BK      64

typedef __attribute__((ext_vector_type(8))) short  short8;
typedef __attribute__((ext_vector_type(4))) float  floatx4;

#define KLD   72   // K tile [64 keys][72] bf16, 144B rows
#define VTLD  72   // V^T tile [64 d][72] bf16
#define PLD   72   // P tile per wave [16 q][72] bf16
#define OLD   65   // epilogue fp32 transpose pitch

#define VTOFF 9216             // 64*72*2
#define POFF  18432            // 2*9216
#define SMEM_BYTES 27648       // 18432 + 4*16*72*2

__device__ __forceinline__ short f2bf(float x) {
  union { __hip_bfloat16 h; short s; } u;
  u.h = __float2bfloat16(x);
  return u.s;
}
__device__ __forceinline__ unsigned pk2(float lo, float hi) {
  union { __hip_bfloat16 h; unsigned short s; } a, b;
  a.h = __float2bfloat16(lo);
  b.h = __float2bfloat16(hi);
  return (unsigned)a.s | ((unsigned)b.s << 16);
}

__global__ __launch_bounds__(256, 2)
void fa_fwd(const float* __restrict__ Qg, const float* __restrict__ Kg,
            const float* __restrict__ Vg, float* __restrict__ Og)
{
  __shared__ char smem[SMEM_BYTES];
  short* Klds  = (short*)smem;
  short* Vtlds = (short*)(smem + VTOFF);

  const int tid  = threadIdx.x;
  const int wv   = tid >> 6;
  const int lane = tid & 63;
  const int col  = lane & 15;
  const int quad = lane >> 4;
  short* Plds = (short*)(smem + POFF) + wv * (16 * PLD);
  float* Olds = (float*)smem + wv * (16 * OLD);

  const int bh = blockIdx.x >> 4;
  const int qi = blockIdx.x & 15;

  const float qscale = 0.18033688011112042f;   // log2(e)/sqrt(64): exp2-domain softmax
  const float* Kb = Kg + (size_t)bh * S_LEN * D_DIM;
  const float* Vb = Vg + (size_t)bh * S_LEN * D_DIM;
  const float* Qb = Qg + (size_t)bh * S_LEN * D_DIM;
  float*       Ob = Og + (size_t)bh * S_LEN * D_DIM;

  // staging thread mappings
  const int krow = tid >> 2;          // K: row (key) 0..63
  const int kcb  = (tid & 3) * 16;    // K: col base (d), 16 floats per thread
  const int kp2  = tid & 31;          // V: key-pair 0..31
  const int dbs  = (tid >> 5) * 8;    // V: d base, 8 d per thread

  float4 kr[4], vr[4];                // prefetch registers (next tile)

  for (int pass = 0; pass < 2; ++pass) {
    const int qblk = pass ? qi : 31 - qi;     // complementary pair: total 33 iters/block
    const int q0   = qblk * 64;
    const int nit  = qblk + 1;
    const int qw   = q0 + wv * 16;

    // ---- Q fragments (B-operand): b[j] = Q[q=col][d = h*32 + quad*8 + j] ----
    short8 qf[2];
#pragma unroll
    for (int h = 0; h < 2; ++h) {
      const float* qp = Qb + (size_t)(qw + col) * D_DIM + h * 32 + quad * 8;
      float4 a = *(const float4*)qp;
      float4 b = *(const float4*)(qp + 4);
      short8 f;
      f[0]=f2bf(a.x*qscale); f[1]=f2bf(a.y*qscale); f[2]=f2bf(a.z*qscale); f[3]=f2bf(a.w*qscale);
      f[4]=f2bf(b.x*qscale); f[5]=f2bf(b.y*qscale); f[6]=f2bf(b.z*qscale); f[7]=f2bf(b.w*qscale);
      qf[h] = f;
    }

    floatx4 o[4];
#pragma unroll
    for (int dt = 0; dt < 4; ++dt) o[dt] = (floatx4){0.f,0.f,0.f,0.f};
    float m_run = -3.0e38f, l_run = 0.f;

    // ---- prefetch tile 0 into registers ----
    {
      const float* p = Kb + (size_t)krow * D_DIM + kcb;
      kr[0] = *(const float4*)p;       kr[1] = *(const float4*)(p + 4);
      kr[2] = *(const float4*)(p + 8); kr[3] = *(const float4*)(p + 12);
      const float* pv = Vb + (size_t)(2 * kp2) * D_DIM + dbs;
      vr[0] = *(const float4*)pv;        vr[1] = *(const float4*)(pv + 4);
      vr[2] = *(const float4*)(pv + 64); vr[3] = *(const float4*)(pv + 68);
    }

    for (int it = 0; it < nit; ++it) {
      __syncthreads();                 // prev iter's LDS reads done

      // ---- regs -> LDS (bf16) ----
      {
        const float* f = (const float*)kr;
        short8 f0, f1;
        f0[0]=f2bf(f[0]);  f0[1]=f2bf(f[1]);  f0[2]=f2bf(f[2]);  f0[3]=f2bf(f[3]);
        f0[4]=f2bf(f[4]);  f0[5]=f2bf(f[5]);  f0[6]=f2bf(f[6]);  f0[7]=f2bf(f[7]);
        f1[0]=f2bf(f[8]);  f1[1]=f2bf(f[9]);  f1[2]=f2bf(f[10]); f1[3]=f2bf(f[11]);
        f1[4]=f2bf(f[12]); f1[5]=f2bf(f[13]); f1[6]=f2bf(f[14]); f1[7]=f2bf(f[15]);
        *(short8*)&Klds[krow * KLD + kcb]     = f0;
        *(short8*)&Klds[krow * KLD + kcb + 8] = f1;
        const float* g = (const float*)vr;   // g[0..7]=V[k0][d..], g[8..15]=V[k0+1][d..]
#pragma unroll
        for (int i = 0; i < 8; ++i)
          *(unsigned*)&Vtlds[(dbs + i) * VTLD + 2 * kp2] = pk2(g[i], g[8 + i]);
      }
      __syncthreads();

      // ---- prefetch next tile (stays in flight through compute) ----
      if (it + 1 < nit) {
        const int kb2 = (it + 1) * BK;
        const float* p = Kb + (size_t)(kb2 + krow) * D_DIM + kcb;
        kr[0] = *(const float4*)p;       kr[1] = *(const float4*)(p + 4);
        kr[2] = *(const float4*)(p + 8); kr[3] = *(const float4*)(p + 12);
        const float* pv = Vb + (size_t)(kb2 + 2 * kp2) * D_DIM + dbs;
        vr[0] = *(const float4*)pv;        vr[1] = *(const float4*)(pv + 4);
        vr[2] = *(const float4*)(pv + 64); vr[3] = *(const float4*)(pv + 68);
      }

      // ---- S^T = K · Q^T ----
      short8 kf[4][2];
#pragma unroll
      for (int kt = 0; kt < 4; ++kt)
#pragma unroll
        for (int h = 0; h < 2; ++h)
          kf[kt][h] = *(short8*)&Klds[(kt * 16 + col) * KLD + h * 32 + quad * 8];

      floatx4 st[4];
#pragma unroll
      for (int kt = 0; kt < 4; ++kt) {
        floatx4 c = (floatx4){0.f,0.f,0.f,0.f};
        c = __builtin_amdgcn_mfma_f32_16x16x32_bf16(kf[kt][0], qf[0], c, 0, 0, 0);
        c = __builtin_amdgcn_mfma_f32_16x16x32_bf16(kf[kt][1], qf[1], c, 0, 0, 0);
        st[kt] = c;
      }

      // ---- causal mask: only the diagonal (last) iteration needs it ----
      if (it == nit - 1) {
        const int qg = qw + col;
        const int kb = it * BK;
#pragma unroll
        for (int kt = 0; kt < 4; ++kt)
#pragma unroll
          for (int r = 0; r < 4; ++r)
            if (kb + kt * 16 + quad * 4 + r > qg) st[kt][r] = -3.0e38f;
      }

      // ---- online softmax (exp2 domain); keys live on quad -> 2 shuffles ----
      float mx = st[0][0];
#pragma unroll
      for (int kt = 0; kt < 4; ++kt)
#pragma unroll
        for (int r = 0; r < 4; ++r) mx = fmaxf(mx, st[kt][r]);
      mx = fmaxf(mx, __shfl_xor(mx, 16));
      mx = fmaxf(mx, __shfl_xor(mx, 32));
      const float mnew  = fmaxf(m_run, mx);
      const float alpha = __builtin_amdgcn_exp2f(m_run - mnew);
      m_run = mnew;
      float sum = 0.f;
#pragma unroll
      for (int kt = 0; kt < 4; ++kt)
#pragma unroll
        for (int r = 0; r < 4; ++r) {
          const float p = __builtin_amdgcn_exp2f(st[kt][r] - mnew);
          st[kt][r] = p;
          sum += p;
        }
      sum += __shfl_xor(sum, 16);
      sum += __shfl_xor(sum, 32);
      l_run = l_run * alpha + sum;
#pragma unroll
      for (int dt = 0; dt < 4; ++dt)
#pragma unroll
        for (int r = 0; r < 4; ++r) o[dt][r] *= alpha;

      // ---- P (C-layout) -> LDS P[q][k]; same-wave region, no barrier needed ----
#pragma unroll
      for (int kt = 0; kt < 4; ++kt) {
        *(unsigned*)&Plds[col * PLD + kt * 16 + quad * 4]     = pk2(st[kt][0], st[kt][1]);
        *(unsigned*)&Plds[col * PLD + kt * 16 + quad * 4 + 2] = pk2(st[kt][2], st[kt][3]);
      }
      short8 pf0 = *(short8*)&Plds[col * PLD + quad * 8];
      short8 pf1 = *(short8*)&Plds[col * PLD + 32 + quad * 8];

      // ---- O^T += V^T · P^T ----
#pragma unroll
      for (int dt = 0; dt < 4; ++dt) {
        short8 vf0 = *(short8*)&Vtlds[(dt * 16 + col) * VTLD + quad * 8];
        short8 vf1 = *(short8*)&Vtlds[(dt * 16 + col) * VTLD + 32 + quad * 8];
        o[dt] = __builtin_amdgcn_mfma_f32_16x16x32_bf16(vf0, pf0, o[dt], 0, 0, 0);
        o[dt] = __builtin_amdgcn_mfma_f32_16x16x32_bf16(vf1, pf1, o[dt], 0, 0, 0);
      }
    }

    // ---- epilogue: normalize, transpose via LDS, coalesced float4 stores ----
    __syncthreads();
    const float inv = 1.0f / l_run;
#pragma unroll
    for (int dt = 0; dt < 4; ++dt)
#pragma unroll
      for (int r = 0; r < 4; ++r)
        Olds[col * OLD + dt * 16 + quad * 4 + r] = o[dt][r] * inv;
#pragma unroll
    for (int it2 = 0; it2 < 4; ++it2) {
      const int ql = it2 * 4 + quad;
      float4 w;
      w.x = Olds[ql * OLD + col * 4 + 0];
      w.y = Olds[ql * OLD + col * 4 + 1];
      w.z = Olds[ql * OLD + col * 4 + 2];
      w.w = Olds[ql * OLD + col * 4 + 3];
      *(float4*)(Ob + (size_t)(qw + ql) * D_DIM + col * 4) = w;
    }
  }
}

extern "C" void kernel_launch(void* const* d_in, const int* in_sizes, int n_in,
                              void* d_out, int out_size, void* d_ws, size_t ws_size,
                              hipStream_t stream) {
  const float* Q = (const float*)d_in[0];
  const float* K = (const float*)d_in[1];
  const float* V = (const float*)d_in[2];
  float* O = (float*)d_out;
  dim3 grid(32 * 16);   // (b*H+h) * 16 complementary q-block pairs
  dim3 block(256);
  hipLaunchKernelGGL(fa_fwd, grid, block, 0, stream, Q, K, V, O);
}